// Round 1
// baseline (548.059 us; speedup 1.0000x reference)
//
#include <hip/hip_runtime.h>
#include <math.h>

// B=batch, S=state_dim, D=image channels, N=spatial positions
#define BB 128
#define SS 1024
#define DD 512
#define NN 784
#define NQ 196      // float4 slots per row (784/4)
#define QCH 8       // d-chunks per batch for k3a (DC=64 rows each)
#define DC 64       // d rows per k3a block

__device__ __forceinline__ float wave_reduce_sum(float x) {
#pragma unroll
  for (int m = 32; m > 0; m >>= 1) x += __shfl_xor(x, m, 64);
  return x;
}
__device__ __forceinline__ float wave_reduce_max(float x) {
#pragma unroll
  for (int m = 32; m > 0; m >>= 1) x = fmaxf(x, __shfl_xor(x, m, 64));
  return x;
}

// K1: v[k] = sum_j Wa[j] * Wc[j, k],  k in [0, 2D).  v pre-zeroed by memsetAsync.
__global__ void k1_v(const float* __restrict__ Wa, const float* __restrict__ Wc,
                     float* __restrict__ v) {
  int k = blockIdx.x * 256 + threadIdx.x;
  int j0 = blockIdx.y * 32;
  float acc = 0.f;
#pragma unroll
  for (int j = 0; j < 32; ++j)
    acc += Wa[j0 + j] * Wc[(size_t)(j0 + j) * (2 * DD) + k];
  atomicAdd(&v[k], acc);
}

// K2: w[b,d] = (in_state[b,:]·Wq[d,:] + bq[d]) * v[d] + v[D+d]
__global__ void k2_w(const float* __restrict__ in_state, const float* __restrict__ Wq,
                     const float* __restrict__ bq, const float* __restrict__ v,
                     float* __restrict__ w) {
  __shared__ float st[SS];
  int b = blockIdx.y;
  int t = threadIdx.x, lane = t & 63, wv = t >> 6;
  ((float4*)st)[t] = ((const float4*)(in_state + (size_t)b * SS))[t];
  __syncthreads();
  const float4* st4 = (const float4*)st;
  float4 s0 = st4[lane], s1 = st4[lane + 64], s2 = st4[lane + 128], s3 = st4[lane + 192];
  int d0 = blockIdx.x * 32 + wv * 8;
  float acc[8];
#pragma unroll
  for (int r = 0; r < 8; ++r) {
    const float4* q4 = (const float4*)(Wq + (size_t)(d0 + r) * SS);
    float4 a0 = q4[lane], a1 = q4[lane + 64], a2 = q4[lane + 128], a3 = q4[lane + 192];
    acc[r] = a0.x * s0.x + a0.y * s0.y + a0.z * s0.z + a0.w * s0.w
           + a1.x * s1.x + a1.y * s1.y + a1.z * s1.z + a1.w * s1.w
           + a2.x * s2.x + a2.y * s2.y + a2.z * s2.z + a2.w * s2.w
           + a3.x * s3.x + a3.y * s3.y + a3.z * s3.z + a3.w * s3.w;
  }
#pragma unroll
  for (int r = 0; r < 8; ++r) acc[r] = wave_reduce_sum(acc[r]);
  if (lane == 0) {
#pragma unroll
    for (int r = 0; r < 8; ++r) {
      int d = d0 + r;
      w[(size_t)b * DD + d] = (acc[r] + bq[d]) * v[d] + v[DD + d];
    }
  }
}

// K3a: partial logits. Block (q, b) owns 64 d-rows of image[b], streams them
// LINEARLY (100% lane efficiency, fully coalesced float4), accumulating
// w[d]*x into component-major LDS planes l[4][196] via ds_add_f32, then
// dumps the 784-float partial to Lpart[b][q][:].
// grid (QCH=8, B) = 1024 blocks, block 256 (4 waves). 12544 float4 per block
// = exactly 49 iters per thread.
__global__ void k3a_logits(const float* __restrict__ image, const float* __restrict__ w,
                           float* __restrict__ Lpart) {
  __shared__ float wl[DC];
  __shared__ float l[4][NQ];
  int b = blockIdx.y, q = blockIdx.x;
  int t = threadIdx.x;
  if (t < DC) wl[t] = w[(size_t)b * DD + q * DC + t];
  float* lf = &l[0][0];
  lf[t] = 0.f; lf[t + 256] = 0.f; lf[t + 512] = 0.f;
  if (t < 16) lf[t + 768] = 0.f;
  __syncthreads();
  const float4* src = (const float4*)image + ((size_t)b * DD * NN + (size_t)q * DC * NN) / 4;
  int s = t % NQ;         // float4 slot within row
  int d = t / NQ;         // local d row (0..63)
#pragma unroll 7
  for (int i = 0; i < 49; ++i) {
    float4 x = src[t + 256 * i];
    float wd = wl[d];
    atomicAdd(&l[0][s], wd * x.x);
    atomicAdd(&l[1][s], wd * x.y);
    atomicAdd(&l[2][s], wd * x.z);
    atomicAdd(&l[3][s], wd * x.w);
    // advance linear index by 256 float4: 256 = 196 + 60
    s += 60; d += 1;
    int ov = (s >= NQ);
    s -= NQ * ov; d += ov;
  }
  __syncthreads();
  if (t < NQ) {
    float4 o;
    o.x = l[0][t]; o.y = l[1][t]; o.z = l[2][t]; o.w = l[3][t];
    ((float4*)Lpart)[((size_t)b * QCH + q) * NQ + t] = o;
  }
}

// K3b: global softmax over n per batch. Sums the QCH partials, computes
// attn[b,n] = exp(l-M)/Z (fully normalized — replaces old k5_combine).
// grid B, block 256 (4 waves; slots handled by t<196).
__global__ void k3b_softmax(const float* __restrict__ Lpart, float* __restrict__ attn) {
  __shared__ float red[8];
  int b = blockIdx.x, t = threadIdx.x, lane = t & 63, wv = t >> 6;
  float4 l4 = {0.f, 0.f, 0.f, 0.f};
  if (t < NQ) {
#pragma unroll
    for (int q = 0; q < QCH; ++q) {
      float4 p = ((const float4*)Lpart)[((size_t)b * QCH + q) * NQ + t];
      l4.x += p.x; l4.y += p.y; l4.z += p.z; l4.w += p.w;
    }
  }
  float m = (t < NQ) ? fmaxf(fmaxf(l4.x, l4.y), fmaxf(l4.z, l4.w)) : -1e30f;
  m = wave_reduce_max(m);
  if (lane == 0) red[wv] = m;
  __syncthreads();
  float M = fmaxf(fmaxf(red[0], red[1]), fmaxf(red[2], red[3]));
  float4 u = {0.f, 0.f, 0.f, 0.f};
  float zs = 0.f;
  if (t < NQ) {
    u.x = __expf(l4.x - M); u.y = __expf(l4.y - M);
    u.z = __expf(l4.z - M); u.w = __expf(l4.w - M);
    zs = u.x + u.y + u.z + u.w;
  }
  zs = wave_reduce_sum(zs);
  if (lane == 0) red[4 + wv] = zs;
  __syncthreads();
  float Z = red[4] + red[5] + red[6] + red[7];
  float inv = 1.0f / Z;
  if (t < NQ) {
    u.x *= inv; u.y *= inv; u.z *= inv; u.w *= inv;
    ((float4*)attn)[(size_t)b * NQ + t] = u;
  }
}

// K3c: pooled[b,d] = sum_n attn[b,n]*image[b,d,n]. Image re-read is LLC-hot.
// grid (8, B) = 1024 blocks, block 512 (8 waves x 8 rows each). attn held in
// 4 float4 regs per lane (slots lane, +64, +128, +192<4).
__global__ void k3c_pool(const float* __restrict__ image, const float* __restrict__ attn,
                         float* __restrict__ pooled) {
  int b = blockIdx.y, g = blockIdx.x;
  int t = threadIdx.x, lane = t & 63, wv = t >> 6;
  const float4* a4 = (const float4*)attn + (size_t)b * NQ;
  float4 A0 = a4[lane], A1 = a4[lane + 64], A2 = a4[lane + 128];
  float4 A3 = {0.f, 0.f, 0.f, 0.f};
  if (lane < 4) A3 = a4[lane + 192];
  int d0 = g * 64 + wv * 8;
  const float4* src = (const float4*)image + (size_t)b * DD * NQ;
#pragma unroll 4
  for (int r = 0; r < 8; ++r) {
    const float4* row = src + (size_t)(d0 + r) * NQ;
    float4 x0 = row[lane], x1 = row[lane + 64], x2 = row[lane + 128];
    float acc = A0.x * x0.x + A0.y * x0.y + A0.z * x0.z + A0.w * x0.w
              + A1.x * x1.x + A1.y * x1.y + A1.z * x1.z + A1.w * x1.w
              + A2.x * x2.x + A2.y * x2.y + A2.z * x2.z + A2.w * x2.w;
    if (lane < 4) {
      float4 x3 = row[lane + 192];
      acc += A3.x * x3.x + A3.y * x3.y + A3.z * x3.z + A3.w * x3.w;
    }
    acc = wave_reduce_sum(acc);
    if (lane == 0) pooled[(size_t)b * DD + d0 + r] = acc;
  }
}

// K6: out[b,s] = pooled[b,:]·Wo[s,:] + bo[s]
__global__ void k6_out(const float* __restrict__ pooled, const float* __restrict__ Wo,
                       const float* __restrict__ bo, float* __restrict__ out) {
  __shared__ float p_s[DD];
  int b = blockIdx.y, t = threadIdx.x, lane = t & 63, wv = t >> 6;
  ((float2*)p_s)[t] = ((const float2*)(pooled + (size_t)b * DD))[t];
  __syncthreads();
  const float4* p4 = (const float4*)p_s;
  float4 p0 = p4[lane], p1 = p4[lane + 64];
  int s0 = blockIdx.x * 32 + wv * 8;
  float acc[8];
#pragma unroll
  for (int r = 0; r < 8; ++r) {
    const float4* wo4 = (const float4*)(Wo + (size_t)(s0 + r) * DD);
    float4 x0 = wo4[lane], x1 = wo4[lane + 64];
    acc[r] = x0.x * p0.x + x0.y * p0.y + x0.z * p0.z + x0.w * p0.w
           + x1.x * p1.x + x1.y * p1.y + x1.z * p1.z + x1.w * p1.w;
  }
#pragma unroll
  for (int r = 0; r < 8; ++r) acc[r] = wave_reduce_sum(acc[r]);
  if (lane == 0) {
#pragma unroll
    for (int r = 0; r < 8; ++r) out[(size_t)b * SS + s0 + r] = acc[r] + bo[s0 + r];
  }
}

extern "C" void kernel_launch(void* const* d_in, const int* in_sizes, int n_in,
                              void* d_out, int out_size, void* d_ws, size_t ws_size,
                              hipStream_t stream) {
  const float* in_state = (const float*)d_in[0];
  const float* image    = (const float*)d_in[1];
  const float* Wq       = (const float*)d_in[2];
  const float* bq       = (const float*)d_in[3];
  const float* Wc       = (const float*)d_in[4];
  const float* Wa       = (const float*)d_in[6];
  const float* Wo       = (const float*)d_in[8];
  const float* bo       = (const float*)d_in[9];
  float* out = (float*)d_out;

  // workspace layout (floats): ~4.1 MB total
  float* ws     = (float*)d_ws;
  float* v      = ws;                                // 2D             = 1024
  float* w      = v + 2 * DD;                        // B*D            = 65536
  float* Lpart  = w + (size_t)BB * DD;               // B*QCH*784      = 802816
  float* attn   = Lpart + (size_t)BB * QCH * NN;     // B*784          = 100352
  float* pooled = attn + (size_t)BB * NN;            // B*D            = 65536

  hipMemsetAsync(v, 0, 2 * DD * sizeof(float), stream);
  k1_v<<<dim3(4, 16), 256, 0, stream>>>(Wa, Wc, v);
  k2_w<<<dim3(16, BB), 256, 0, stream>>>(in_state, Wq, bq, v, w);
  k3a_logits<<<dim3(QCH, BB), 256, 0, stream>>>(image, w, Lpart);
  k3b_softmax<<<BB, 256, 0, stream>>>(Lpart, attn);
  k3c_pool<<<dim3(8, BB), 512, 0, stream>>>(image, attn, pooled);
  k6_out<<<dim3(32, BB), 256, 0, stream>>>(pooled, Wo, bo, out);
}

// Round 3
// 370.313 us; speedup vs baseline: 1.4800x; 1.4800x over previous
//
#include <hip/hip_runtime.h>
#include <math.h>

// B=batch, S=state_dim, D=image channels, N=spatial positions
#define BB 128
#define SS 1024
#define DD 512
#define NN 784
#define NQ 196      // float4 slots per row (784/4)
#define QCH 8       // d-chunks per batch for k3a (DC=64 rows each)
#define DC 64       // d rows per k3a block

__device__ __forceinline__ float wave_reduce_sum(float x) {
#pragma unroll
  for (int m = 32; m > 0; m >>= 1) x += __shfl_xor(x, m, 64);
  return x;
}
__device__ __forceinline__ float wave_reduce_max(float x) {
#pragma unroll
  for (int m = 32; m > 0; m >>= 1) x = fmaxf(x, __shfl_xor(x, m, 64));
  return x;
}

// K1: v[k] = sum_j Wa[j] * Wc[j, k],  k in [0, 2D).  v pre-zeroed by memsetAsync.
__global__ void k1_v(const float* __restrict__ Wa, const float* __restrict__ Wc,
                     float* __restrict__ v) {
  int k = blockIdx.x * 256 + threadIdx.x;
  int j0 = blockIdx.y * 32;
  float acc = 0.f;
#pragma unroll
  for (int j = 0; j < 32; ++j)
    acc += Wa[j0 + j] * Wc[(size_t)(j0 + j) * (2 * DD) + k];
  atomicAdd(&v[k], acc);
}

// K2: w[b,d] = (in_state[b,:]·Wq[d,:] + bq[d]) * v[d] + v[D+d]
__global__ void k2_w(const float* __restrict__ in_state, const float* __restrict__ Wq,
                     const float* __restrict__ bq, const float* __restrict__ v,
                     float* __restrict__ w) {
  __shared__ float st[SS];
  int b = blockIdx.y;
  int t = threadIdx.x, lane = t & 63, wv = t >> 6;
  ((float4*)st)[t] = ((const float4*)(in_state + (size_t)b * SS))[t];
  __syncthreads();
  const float4* st4 = (const float4*)st;
  float4 s0 = st4[lane], s1 = st4[lane + 64], s2 = st4[lane + 128], s3 = st4[lane + 192];
  int d0 = blockIdx.x * 32 + wv * 8;
  float acc[8];
#pragma unroll
  for (int r = 0; r < 8; ++r) {
    const float4* q4 = (const float4*)(Wq + (size_t)(d0 + r) * SS);
    float4 a0 = q4[lane], a1 = q4[lane + 64], a2 = q4[lane + 128], a3 = q4[lane + 192];
    acc[r] = a0.x * s0.x + a0.y * s0.y + a0.z * s0.z + a0.w * s0.w
           + a1.x * s1.x + a1.y * s1.y + a1.z * s1.z + a1.w * s1.w
           + a2.x * s2.x + a2.y * s2.y + a2.z * s2.z + a2.w * s2.w
           + a3.x * s3.x + a3.y * s3.y + a3.z * s3.z + a3.w * s3.w;
  }
#pragma unroll
  for (int r = 0; r < 8; ++r) acc[r] = wave_reduce_sum(acc[r]);
  if (lane == 0) {
#pragma unroll
    for (int r = 0; r < 8; ++r) {
      int d = d0 + r;
      w[(size_t)b * DD + d] = (acc[r] + bq[d]) * v[d] + v[DD + d];
    }
  }
}

// K3a: partial logits, REGISTER accumulation (no LDS atomics).
// grid (QCH=8, B) = 1024 blocks, block 256. Thread t owns float4 slot t
// (t<196 active; the 196 active lanes issue one contiguous 3136B request
// per iteration, so every 64B line is fully utilized — lane idleness is
// free on a BW-bound stream). Loops the block's 64 d-rows; per iter one
// coalesced float4 load + 4 FMA into registers. Writes the 784-float
// partial to Lpart[b][q][:] coalesced.
__global__ void k3a_logits(const float* __restrict__ image, const float* __restrict__ w,
                           float* __restrict__ Lpart) {
  __shared__ float wl[DC];
  int b = blockIdx.y, q = blockIdx.x;
  int t = threadIdx.x;
  if (t < DC) wl[t] = w[(size_t)b * DD + q * DC + t];
  __syncthreads();
  const float4* src = (const float4*)image + (size_t)(b * DD + q * DC) * NQ;
  if (t < NQ) {
    float4 acc = {0.f, 0.f, 0.f, 0.f};
#pragma unroll 8
    for (int d = 0; d < DC; ++d) {
      float4 x = src[(size_t)d * NQ + t];
      float wd = wl[d];
      acc.x += wd * x.x; acc.y += wd * x.y; acc.z += wd * x.z; acc.w += wd * x.w;
    }
    ((float4*)Lpart)[((size_t)b * QCH + q) * NQ + t] = acc;
  }
}

// K3b: global softmax over n per batch. Sums the QCH partials, computes
// attn[b,n] = exp(l-M)/Z (fully normalized).
// grid B, block 256 (4 waves; slots handled by t<196).
__global__ void k3b_softmax(const float* __restrict__ Lpart, float* __restrict__ attn) {
  __shared__ float red[8];
  int b = blockIdx.x, t = threadIdx.x, lane = t & 63, wv = t >> 6;
  float4 l4 = {0.f, 0.f, 0.f, 0.f};
  if (t < NQ) {
#pragma unroll
    for (int q = 0; q < QCH; ++q) {
      float4 p = ((const float4*)Lpart)[((size_t)b * QCH + q) * NQ + t];
      l4.x += p.x; l4.y += p.y; l4.z += p.z; l4.w += p.w;
    }
  }
  float m = (t < NQ) ? fmaxf(fmaxf(l4.x, l4.y), fmaxf(l4.z, l4.w)) : -1e30f;
  m = wave_reduce_max(m);
  if (lane == 0) red[wv] = m;
  __syncthreads();
  float M = fmaxf(fmaxf(red[0], red[1]), fmaxf(red[2], red[3]));
  float4 u = {0.f, 0.f, 0.f, 0.f};
  float zs = 0.f;
  if (t < NQ) {
    u.x = __expf(l4.x - M); u.y = __expf(l4.y - M);
    u.z = __expf(l4.z - M); u.w = __expf(l4.w - M);
    zs = u.x + u.y + u.z + u.w;
  }
  zs = wave_reduce_sum(zs);
  if (lane == 0) red[4 + wv] = zs;
  __syncthreads();
  float Z = red[4] + red[5] + red[6] + red[7];
  float inv = 1.0f / Z;
  if (t < NQ) {
    u.x *= inv; u.y *= inv; u.z *= inv; u.w *= inv;
    ((float4*)attn)[(size_t)b * NQ + t] = u;
  }
}

// K3c: pooled[b,d] = sum_n attn[b,n]*image[b,d,n]. Image re-read is LLC-hot.
// grid (8, B) = 1024 blocks, block 512 (8 waves x 8 rows each).
__global__ void k3c_pool(const float* __restrict__ image, const float* __restrict__ attn,
                         float* __restrict__ pooled) {
  int b = blockIdx.y, g = blockIdx.x;
  int t = threadIdx.x, lane = t & 63, wv = t >> 6;
  const float4* a4 = (const float4*)attn + (size_t)b * NQ;
  float4 A0 = a4[lane], A1 = a4[lane + 64], A2 = a4[lane + 128];
  float4 A3 = {0.f, 0.f, 0.f, 0.f};
  if (lane < 4) A3 = a4[lane + 192];
  int d0 = g * 64 + wv * 8;
  const float4* src = (const float4*)image + (size_t)b * DD * NQ;
#pragma unroll 4
  for (int r = 0; r < 8; ++r) {
    const float4* row = src + (size_t)(d0 + r) * NQ;
    float4 x0 = row[lane], x1 = row[lane + 64], x2 = row[lane + 128];
    float acc = A0.x * x0.x + A0.y * x0.y + A0.z * x0.z + A0.w * x0.w
              + A1.x * x1.x + A1.y * x1.y + A1.z * x1.z + A1.w * x1.w
              + A2.x * x2.x + A2.y * x2.y + A2.z * x2.z + A2.w * x2.w;
    if (lane < 4) {
      float4 x3 = row[lane + 192];
      acc += A3.x * x3.x + A3.y * x3.y + A3.z * x3.z + A3.w * x3.w;
    }
    acc = wave_reduce_sum(acc);
    if (lane == 0) pooled[(size_t)b * DD + d0 + r] = acc;
  }
}

// K6: out[b,s] = pooled[b,:]·Wo[s,:] + bo[s]
__global__ void k6_out(const float* __restrict__ pooled, const float* __restrict__ Wo,
                       const float* __restrict__ bo, float* __restrict__ out) {
  __shared__ float p_s[DD];
  int b = blockIdx.y, t = threadIdx.x, lane = t & 63, wv = t >> 6;
  ((float2*)p_s)[t] = ((const float2*)(pooled + (size_t)b * DD))[t];
  __syncthreads();
  const float4* p4 = (const float4*)p_s;
  float4 p0 = p4[lane], p1 = p4[lane + 64];
  int s0 = blockIdx.x * 32 + wv * 8;
  float acc[8];
#pragma unroll
  for (int r = 0; r < 8; ++r) {
    const float4* wo4 = (const float4*)(Wo + (size_t)(s0 + r) * DD);
    float4 x0 = wo4[lane], x1 = wo4[lane + 64];
    acc[r] = x0.x * p0.x + x0.y * p0.y + x0.z * p0.z + x0.w * p0.w
           + x1.x * p1.x + x1.y * p1.y + x1.z * p1.z + x1.w * p1.w;
  }
#pragma unroll
  for (int r = 0; r < 8; ++r) acc[r] = wave_reduce_sum(acc[r]);
  if (lane == 0) {
#pragma unroll
    for (int r = 0; r < 8; ++r) out[(size_t)b * SS + s0 + r] = acc[r] + bo[s0 + r];
  }
}

extern "C" void kernel_launch(void* const* d_in, const int* in_sizes, int n_in,
                              void* d_out, int out_size, void* d_ws, size_t ws_size,
                              hipStream_t stream) {
  const float* in_state = (const float*)d_in[0];
  const float* image    = (const float*)d_in[1];
  const float* Wq       = (const float*)d_in[2];
  const float* bq       = (const float*)d_in[3];
  const float* Wc       = (const float*)d_in[4];
  const float* Wa       = (const float*)d_in[6];
  const float* Wo       = (const float*)d_in[8];
  const float* bo       = (const float*)d_in[9];
  float* out = (float*)d_out;

  // workspace layout (floats): ~4.1 MB total
  float* ws     = (float*)d_ws;
  float* v      = ws;                                // 2D             = 1024
  float* w      = v + 2 * DD;                        // B*D            = 65536
  float* Lpart  = w + (size_t)BB * DD;               // B*QCH*784      = 802816
  float* attn   = Lpart + (size_t)BB * QCH * NN;     // B*784          = 100352
  float* pooled = attn + (size_t)BB * NN;            // B*D            = 65536

  hipMemsetAsync(v, 0, 2 * DD * sizeof(float), stream);
  k1_v<<<dim3(4, 16), 256, 0, stream>>>(Wa, Wc, v);
  k2_w<<<dim3(16, BB), 256, 0, stream>>>(in_state, Wq, bq, v, w);
  k3a_logits<<<dim3(QCH, BB), 256, 0, stream>>>(image, w, Lpart);
  k3b_softmax<<<BB, 256, 0, stream>>>(Lpart, attn);
  k3c_pool<<<dim3(8, BB), 512, 0, stream>>>(image, attn, pooled);
  k6_out<<<dim3(32, BB), 256, 0, stream>>>(pooled, Wo, bo, out);
}

// Round 6
// 369.152 us; speedup vs baseline: 1.4846x; 1.0031x over previous
//
#include <hip/hip_runtime.h>
#include <math.h>

// B=batch, S=state_dim, D=image channels, N=spatial positions
#define BB 128
#define SS 1024
#define DD 512
#define NN 784
#define NQ 196      // float4 slots per row (784/4)
#define QCH 8       // d-chunks per batch for k3a (DC=64 rows each)
#define DC 64       // d rows per k3a block

__device__ __forceinline__ float wave_reduce_sum(float x) {
#pragma unroll
  for (int m = 32; m > 0; m >>= 1) x += __shfl_xor(x, m, 64);
  return x;
}
__device__ __forceinline__ float wave_reduce_max(float x) {
#pragma unroll
  for (int m = 32; m > 0; m >>= 1) x = fmaxf(x, __shfl_xor(x, m, 64));
  return x;
}

// K1: v[k] = sum_j Wa[j] * Wc[j, k],  k in [0, 2D).  v pre-zeroed by memsetAsync.
__global__ void k1_v(const float* __restrict__ Wa, const float* __restrict__ Wc,
                     float* __restrict__ v) {
  int k = blockIdx.x * 256 + threadIdx.x;
  int j0 = blockIdx.y * 32;
  float acc = 0.f;
#pragma unroll
  for (int j = 0; j < 32; ++j)
    acc += Wa[j0 + j] * Wc[(size_t)(j0 + j) * (2 * DD) + k];
  atomicAdd(&v[k], acc);
}

// K2: w[b,d] = (in_state[b,:]·Wq[d,:] + bq[d]) * v[d] + v[D+d]
__global__ void k2_w(const float* __restrict__ in_state, const float* __restrict__ Wq,
                     const float* __restrict__ bq, const float* __restrict__ v,
                     float* __restrict__ w) {
  __shared__ float st[SS];
  int b = blockIdx.y;
  int t = threadIdx.x, lane = t & 63, wv = t >> 6;
  ((float4*)st)[t] = ((const float4*)(in_state + (size_t)b * SS))[t];
  __syncthreads();
  const float4* st4 = (const float4*)st;
  float4 s0 = st4[lane], s1 = st4[lane + 64], s2 = st4[lane + 128], s3 = st4[lane + 192];
  int d0 = blockIdx.x * 32 + wv * 8;
  float acc[8];
#pragma unroll
  for (int r = 0; r < 8; ++r) {
    const float4* q4 = (const float4*)(Wq + (size_t)(d0 + r) * SS);
    float4 a0 = q4[lane], a1 = q4[lane + 64], a2 = q4[lane + 128], a3 = q4[lane + 192];
    acc[r] = a0.x * s0.x + a0.y * s0.y + a0.z * s0.z + a0.w * s0.w
           + a1.x * s1.x + a1.y * s1.y + a1.z * s1.z + a1.w * s1.w
           + a2.x * s2.x + a2.y * s2.y + a2.z * s2.z + a2.w * s2.w
           + a3.x * s3.x + a3.y * s3.y + a3.z * s3.z + a3.w * s3.w;
  }
#pragma unroll
  for (int r = 0; r < 8; ++r) acc[r] = wave_reduce_sum(acc[r]);
  if (lane == 0) {
#pragma unroll
    for (int r = 0; r < 8; ++r) {
      int d = d0 + r;
      w[(size_t)b * DD + d] = (acc[r] + bq[d]) * v[d] + v[DD + d];
    }
  }
}

// K3a: partial logits, REGISTER accumulation (no LDS atomics).
// grid (QCH=8, B) = 1024 blocks, block 256. Thread t owns float4 slot t
// (t<196 active; the 196 active lanes issue one contiguous 3136B request
// per iteration so every 64B line is fully used). Loops the block's 64
// d-rows; one coalesced float4 load + 4 FMA per iter. Coalesced partial
// write to Lpart[b][q][:].
__global__ void k3a_logits(const float* __restrict__ image, const float* __restrict__ w,
                           float* __restrict__ Lpart) {
  __shared__ float wl[DC];
  int b = blockIdx.y, q = blockIdx.x;
  int t = threadIdx.x;
  if (t < DC) wl[t] = w[(size_t)b * DD + q * DC + t];
  __syncthreads();
  const float4* src = (const float4*)image + (size_t)(b * DD + q * DC) * NQ;
  if (t < NQ) {
    float4 acc = {0.f, 0.f, 0.f, 0.f};
#pragma unroll 8
    for (int d = 0; d < DC; ++d) {
      float4 x = src[(size_t)d * NQ + t];
      float wd = wl[d];
      acc.x += wd * x.x; acc.y += wd * x.y; acc.z += wd * x.z; acc.w += wd * x.w;
    }
    ((float4*)Lpart)[((size_t)b * QCH + q) * NQ + t] = acc;
  }
}

// K3bc: fused softmax + pool. grid (8, B) = 1024 blocks, block 512 (8 waves).
// Phase A (waves 0-3, t<196): sum the QCH Lpart partials (L2-hot, 25 KB),
// global softmax, normalized weights -> u_lds (replicated per block; 8x
// redundancy ~ 25.6 MB aggregate L2 reads, negligible).
// Phase B: pooled[b, g*64 + wv*8 + r] = sum_n u[n]*image[b,d,n], image
// re-read LLC-hot, wave-per-row reduce (verbatim round-3 k3c body with
// attn sourced from LDS instead of global).
__global__ void k3bc_pool(const float* __restrict__ image, const float* __restrict__ Lpart,
                          float* __restrict__ pooled) {
  __shared__ float redm[8], redz[8];
  __shared__ float4 u_lds[NQ];
  int b = blockIdx.y, g = blockIdx.x;
  int t = threadIdx.x, lane = t & 63, wv = t >> 6;
  // ---- phase A: softmax from Lpart ----
  float4 l4 = {0.f, 0.f, 0.f, 0.f};
  if (t < NQ) {
#pragma unroll
    for (int q = 0; q < QCH; ++q) {
      float4 p = ((const float4*)Lpart)[((size_t)b * QCH + q) * NQ + t];
      l4.x += p.x; l4.y += p.y; l4.z += p.z; l4.w += p.w;
    }
  }
  float lm = (t < NQ) ? fmaxf(fmaxf(l4.x, l4.y), fmaxf(l4.z, l4.w)) : -1e30f;
  lm = wave_reduce_max(lm);
  if (lane == 0) redm[wv] = lm;
  __syncthreads();
  float M = fmaxf(fmaxf(redm[0], redm[1]), fmaxf(redm[2], redm[3]));
  float4 u = {0.f, 0.f, 0.f, 0.f};
  float zs = 0.f;
  if (t < NQ) {
    u.x = __expf(l4.x - M); u.y = __expf(l4.y - M);
    u.z = __expf(l4.z - M); u.w = __expf(l4.w - M);
    zs = u.x + u.y + u.z + u.w;
  }
  zs = wave_reduce_sum(zs);
  if (lane == 0) redz[wv] = zs;
  __syncthreads();
  float Z = redz[0] + redz[1] + redz[2] + redz[3];
  float inv = 1.0f / Z;
  if (t < NQ) {
    u.x *= inv; u.y *= inv; u.z *= inv; u.w *= inv;
    u_lds[t] = u;
  }
  __syncthreads();
  // ---- phase B: pool (image LLC-hot) ----
  float4 A0 = u_lds[lane], A1 = u_lds[lane + 64], A2 = u_lds[lane + 128];
  float4 A3 = {0.f, 0.f, 0.f, 0.f};
  if (lane < 4) A3 = u_lds[lane + 192];
  int d0 = g * 64 + wv * 8;
  const float4* src = (const float4*)image + (size_t)b * DD * NQ;
#pragma unroll 4
  for (int r = 0; r < 8; ++r) {
    const float4* row = src + (size_t)(d0 + r) * NQ;
    float4 x0 = row[lane], x1 = row[lane + 64], x2 = row[lane + 128];
    float acc = A0.x * x0.x + A0.y * x0.y + A0.z * x0.z + A0.w * x0.w
              + A1.x * x1.x + A1.y * x1.y + A1.z * x1.z + A1.w * x1.w
              + A2.x * x2.x + A2.y * x2.y + A2.z * x2.z + A2.w * x2.w;
    if (lane < 4) {
      float4 x3 = row[lane + 192];
      acc += A3.x * x3.x + A3.y * x3.y + A3.z * x3.z + A3.w * x3.w;
    }
    acc = wave_reduce_sum(acc);
    if (lane == 0) pooled[(size_t)b * DD + d0 + r] = acc;
  }
}

// K6: out[b,s] = pooled[b,:]·Wo[s,:] + bo[s]
__global__ void k6_out(const float* __restrict__ pooled, const float* __restrict__ Wo,
                       const float* __restrict__ bo, float* __restrict__ out) {
  __shared__ float p_s[DD];
  int b = blockIdx.y, t = threadIdx.x, lane = t & 63, wv = t >> 6;
  ((float2*)p_s)[t] = ((const float2*)(pooled + (size_t)b * DD))[t];
  __syncthreads();
  const float4* p4 = (const float4*)p_s;
  float4 p0 = p4[lane], p1 = p4[lane + 64];
  int s0 = blockIdx.x * 32 + wv * 8;
  float acc[8];
#pragma unroll
  for (int r = 0; r < 8; ++r) {
    const float4* wo4 = (const float4*)(Wo + (size_t)(s0 + r) * DD);
    float4 x0 = wo4[lane], x1 = wo4[lane + 64];
    acc[r] = x0.x * p0.x + x0.y * p0.y + x0.z * p0.z + x0.w * p0.w
           + x1.x * p1.x + x1.y * p1.y + x1.z * p1.z + x1.w * p1.w;
  }
#pragma unroll
  for (int r = 0; r < 8; ++r) acc[r] = wave_reduce_sum(acc[r]);
  if (lane == 0) {
#pragma unroll
    for (int r = 0; r < 8; ++r) out[(size_t)b * SS + s0 + r] = acc[r] + bo[s0 + r];
  }
}

extern "C" void kernel_launch(void* const* d_in, const int* in_sizes, int n_in,
                              void* d_out, int out_size, void* d_ws, size_t ws_size,
                              hipStream_t stream) {
  const float* in_state = (const float*)d_in[0];
  const float* image    = (const float*)d_in[1];
  const float* Wq       = (const float*)d_in[2];
  const float* bq       = (const float*)d_in[3];
  const float* Wc       = (const float*)d_in[4];
  const float* Wa       = (const float*)d_in[6];
  const float* Wo       = (const float*)d_in[8];
  const float* bo       = (const float*)d_in[9];
  float* out = (float*)d_out;

  // workspace layout (floats): ~3.7 MB total
  float* ws     = (float*)d_ws;
  float* v      = ws;                                // 2D             = 1024
  float* w      = v + 2 * DD;                        // B*D            = 65536
  float* Lpart  = w + (size_t)BB * DD;               // B*QCH*784      = 802816
  float* pooled = Lpart + (size_t)BB * QCH * NN;     // B*D            = 65536

  hipMemsetAsync(v, 0, 2 * DD * sizeof(float), stream);
  k1_v<<<dim3(4, 16), 256, 0, stream>>>(Wa, Wc, v);
  k2_w<<<dim3(16, BB), 256, 0, stream>>>(in_state, Wq, bq, v, w);
  k3a_logits<<<dim3(QCH, BB), 256, 0, stream>>>(image, w, Lpart);
  k3bc_pool<<<dim3(8, BB), 512, 0, stream>>>(image, Lpart, pooled);
  k6_out<<<dim3(32, BB), 256, 0, stream>>>(pooled, Wo, bo, out);
}